// Round 8
// baseline (806.142 us; speedup 1.0000x reference)
//
#include <hip/hip_runtime.h>

#define DEV __device__ __forceinline__

typedef float f2 __attribute__((ext_vector_type(2)));

// packed fp32 fma: acc.lo += a.lo*b.lo ; acc.hi += a.hi*b.hi  (CDNA VOP3P)
DEV void pkfma(f2& acc, f2 a, f2 b) {
  asm("v_pk_fma_f32 %0, %1, %2, %0" : "+v"(acc) : "v"(a), "v"(b));
}

template <int CTRL>
DEV float dppf(float x) {
  return __int_as_float(__builtin_amdgcn_update_dpp(
      0, __float_as_int(x), CTRL, 0xF, 0xF, true));
}

// Butterfly sum within each 32-lane half; result broadcast to the half.
DEV float wsum32(float v) {
  v += dppf<0xB1>(v);   // xor1
  v += dppf<0x4E>(v);   // xor2
  v += dppf<0x141>(v);  // xor4
  v += dppf<0x140>(v);  // xor8
#if __has_builtin(__builtin_amdgcn_permlane16_swap)
  {
    auto p = __builtin_amdgcn_permlane16_swap(
        __float_as_uint(v), __float_as_uint(v), false, false);
    v = __uint_as_float(p[0]) + __uint_as_float(p[1]);
  }
#else
  v += __shfl_xor(v, 16, 64);
#endif
  return v;
}

// v[l] + v[l^32]
DEV float halfsum(float v) {
#if __has_builtin(__builtin_amdgcn_permlane32_swap)
  auto p = __builtin_amdgcn_permlane32_swap(
      __float_as_uint(v), __float_as_uint(v), false, false);
  return __uint_as_float(p[0]) + __uint_as_float(p[1]);
#else
  return v + __shfl_xor(v, 32, 64);
#endif
}

DEV float rlane(float v, int l) {
  return __int_as_float(__builtin_amdgcn_readlane(__float_as_int(v), l));
}

#define SLEN 1024
#define NH 8
#define DH 32
#define HSTRIDE 2048
#define RING 16
#define SLOTF 72  // floats per ring slot: dv[32], k[32], B0, pad

// ---------- phase 1: x = softmax32(h), staged into d_out ----------

__global__ __launch_bounds__(256)
void srwm_xsm(const float* __restrict__ h, float* __restrict__ x) {
  int i = blockIdx.x * 256 + threadIdx.x;
  float e = __expf(h[i]);
  x[i] = __fdividef(e, wsum32(e));
}

// ---------- phase 2: async producer/consumer scan. 2 waves, NO barriers ----

// load x chunk [T] into f2 DST[8]
#define LOADX(DST, T)                                                         \
  { const float* xp_ = xb + (size_t)(T) * HSTRIDE + c0;                       \
    _Pragma("unroll") for (int q4 = 0; q4 < 4; ++q4) {                        \
      float4 a_ = *(const float4*)(xp_ + q4 * 4);                             \
      DST[2*q4] = f2{a_.x, a_.y}; DST[2*q4+1] = f2{a_.z, a_.w}; } }

// 3-matrix matvec (producer): V f2[8] -> 3 broadcast scalars
#define MV3(oq, ok, ob, V)                                                    \
  { f2 aq0={0,0},aq1={0,0},ak0={0,0},ak1={0,0},ab0={0,0},ab1={0,0};           \
    _Pragma("unroll") for (int j = 0; j < 8; j += 2) {                        \
      pkfma(aq0, Wq2[j], V[j]); pkfma(aq1, Wq2[j+1], V[j+1]);                 \
      pkfma(ak0, Wk2[j], V[j]); pkfma(ak1, Wk2[j+1], V[j+1]);                 \
      pkfma(ab0, WB2[j], V[j]); pkfma(ab1, WB2[j+1], V[j+1]);                 \
    }                                                                         \
    f2 aq_=aq0+aq1, ak_=ak0+ak1, ab_=ab0+ab1;                                 \
    oq = halfsum(aq_.x+aq_.y); ok = halfsum(ak_.x+ak_.y);                     \
    ob = halfsum(ab_.x+ab_.y); }

// Producer step T. Entering: pAq/pAk/pAb = W_{T-1}x_T ; W regs = W_{T-1};
// XC = x_{T+1} chunks; XO = stale buffer (receives x_{T+2}).
#define PSTEP(T, XC, XO)                                                      \
  {                                                                           \
    int t2_ = (T) + 2; if (t2_ > SLEN - 1) t2_ = SLEN - 1;                    \
    LOADX(XO, t2_);                    /* early issue, used at T+1 end */     \
    float eq_ = __expf(pAq), ek_ = __expf(pAk);                               \
    float qv_ = __fdividef(eq_, wsum32(eq_));                                 \
    float kv_ = __fdividef(ek_, wsum32(ek_));                                 \
    float bs_ = __fdividef(1.f, 1.f + __expf(-pAb));                          \
    float dvv_ = qv_ - kv_;                                                   \
    f2 dvc[8], kc[8];                                                         \
    _Pragma("unroll") for (int j = 0; j < 8; ++j) {                           \
      f2 td_, tk_;                                                            \
      td_.x = __int_as_float(__builtin_amdgcn_ds_bpermute(b4 + 8*j,     __float_as_int(dvv_))); \
      td_.y = __int_as_float(__builtin_amdgcn_ds_bpermute(b4 + 8*j + 4, __float_as_int(dvv_))); \
      tk_.x = __int_as_float(__builtin_amdgcn_ds_bpermute(b4 + 8*j,     __float_as_int(kv_))); \
      tk_.y = __int_as_float(__builtin_amdgcn_ds_bpermute(b4 + 8*j + 4, __float_as_int(kv_))); \
      dvc[j] = td_; kc[j] = tk_;                                              \
    }                                                                         \
    float dq_, dk_, db_;                                                      \
    MV3(dq_, dk_, db_, dvc);           /* d = W_{T-1} dv */                   \
    float B1_ = rlane(bs_, 1), B2_ = rlane(bs_, 2), B3_ = rlane(bs_, 3);      \
    float uq_ = B1_ * dq_, uk_ = B2_ * dk_, ub_ = B3_ * db_;                  \
    /* ---- ring ship: dv, k, B0, then counter (DS-ordered) ---- */           \
    float* sl_ = &ringf[((T) & (RING - 1)) * SLOTF];                          \
    sl_[r] = dvv_; sl_[DH + r] = kv_;                                         \
    if (lane == 0) sl_[2 * DH] = bs_;                                         \
    __builtin_amdgcn_sched_barrier(0);                                        \
    asm volatile("s_waitcnt lgkmcnt(0)");                                     \
    __builtin_amdgcn_sched_barrier(0);                                        \
    *pcv = (T) + 1;                                                           \
    __builtin_amdgcn_sched_barrier(0);                                        \
    /* ---- W <- W_T ---- */                                                  \
    f2 uuq_ = f2{uq_, uq_}, uuk_ = f2{uk_, uk_}, uub_ = f2{ub_, ub_};         \
    _Pragma("unroll") for (int j = 0; j < 8; ++j) {                           \
      pkfma(Wq2[j], uuq_, kc[j]);                                             \
      pkfma(Wk2[j], uuk_, kc[j]);                                             \
      pkfma(WB2[j], uub_, kc[j]);                                             \
    }                                                                         \
    /* ---- preA_{T+1} = W_T x_{T+1} ---- */                                  \
    MV3(pAq, pAk, pAb, XC);                                                   \
    /* ---- overwrite guard (fires when (T)&15==15 only) ---- */              \
    if (((T) & (RING - 1)) == (RING - 1)) {                                   \
      while (*ccv < (T) - (RING - 3)) {}                                      \
    }                                                                         \
  }

// Consumer step T: y_T = Wy_{T-1} x_T ; u_y = B0 (Wy_{T-1} dv) ; update.
#define CSTEP(T, XC)                                                          \
  {                                                                           \
    while (*pcv < (T) + 1) {}                                                 \
    __builtin_amdgcn_sched_barrier(0);                                        \
    const float* sl_ = &ringf[((T) & (RING - 1)) * SLOTF];                    \
    f2 dvc[8], kc[8];                                                         \
    _Pragma("unroll") for (int q4 = 0; q4 < 4; ++q4) {                        \
      float4 a_ = *(const float4*)(sl_ + c0 + q4 * 4);                        \
      dvc[2*q4] = f2{a_.x, a_.y}; dvc[2*q4+1] = f2{a_.z, a_.w};               \
      float4 b_ = *(const float4*)(sl_ + DH + c0 + q4 * 4);                   \
      kc[2*q4] = f2{b_.x, b_.y}; kc[2*q4+1] = f2{b_.z, b_.w};                 \
    }                                                                         \
    float B0_ = sl_[2 * DH];                                                  \
    f2 a0_={0,0}, a1_={0,0};                                                  \
    _Pragma("unroll") for (int j = 0; j < 8; j += 2) {                        \
      pkfma(a0_, Wy2[j], XC[j]); pkfma(a1_, Wy2[j+1], XC[j+1]);               \
    }                                                                         \
    f2 as_ = a0_ + a1_; float yv_ = halfsum(as_.x + as_.y);                   \
    if (lane < DH) xb[(size_t)(T) * HSTRIDE + lane] = yv_;                    \
    int t2_ = (T) + 2; if (t2_ > SLEN - 1) t2_ = SLEN - 1;                    \
    LOADX(XC, t2_);                     /* x_T consumed; recycle buffer */    \
    f2 d0_={0,0}, d1_={0,0};                                                  \
    _Pragma("unroll") for (int j = 0; j < 8; j += 2) {                        \
      pkfma(d0_, Wy2[j], dvc[j]); pkfma(d1_, Wy2[j+1], dvc[j+1]);             \
    }                                                                         \
    f2 ds_ = d0_ + d1_; float uy_ = B0_ * halfsum(ds_.x + ds_.y);             \
    f2 uu_ = f2{uy_, uy_};                                                    \
    _Pragma("unroll") for (int j = 0; j < 8; ++j) pkfma(Wy2[j], uu_, kc[j]);  \
    __builtin_amdgcn_sched_barrier(0);                                        \
    *ccv = (T) + 1;                                                           \
    __builtin_amdgcn_sched_barrier(0);                                        \
  }

__global__ __launch_bounds__(128, 1)
void srwm_scan(const float* __restrict__ Wy0, const float* __restrict__ Wq0,
               const float* __restrict__ Wk0, const float* __restrict__ wb0,
               float* xy) {
  __shared__ float ringf[RING * SLOTF];
  __shared__ int pcnt, ccnt;

  const int bh   = blockIdx.x;        // 0..63
  const int hd   = bh & 7;
  const int w    = threadIdx.x >> 6;  // 0 = producer, 1 = consumer
  const int lane = threadIdx.x & 63;
  const int r    = lane & 31;
  const int c0   = (lane >> 5) * 16;
  const int b4   = c0 * 4;            // bpermute byte base

  volatile int* pcv = &pcnt;
  volatile int* ccv = &ccnt;

  if (threadIdx.x == 0) { pcnt = 0; ccnt = 0; }
  __syncthreads();  // only barrier in the kernel (before wave roles diverge)

  float* xb = xy + bh * DH;  // x/y for this (b,h): [t*HSTRIDE + j]

  if (w == 0) {
    // ================= producer: Wq, Wk, wb recurrence =================
    f2 Wq2[8], Wk2[8], WB2[8];
    {
      const float* pq = Wq0 + (hd * DH + r) * DH + c0;
      const float* pk = Wk0 + (hd * DH + r) * DH + c0;
#pragma unroll
      for (int q4 = 0; q4 < 4; ++q4) {
        float4 a = *(const float4*)(pq + q4 * 4);
        Wq2[2*q4] = f2{a.x, a.y}; Wq2[2*q4+1] = f2{a.z, a.w};
        float4 b = *(const float4*)(pk + q4 * 4);
        Wk2[2*q4] = f2{b.x, b.y}; Wk2[2*q4+1] = f2{b.z, b.w};
      }
      const int kk = r & 3;
      float wbs[16];
#pragma unroll
      for (int j = 0; j < 16; ++j) wbs[j] = wb0[(hd * DH + c0 + j) * 4 + kk];
#pragma unroll
      for (int j = 0; j < 8; ++j) WB2[j] = f2{wbs[2*j], wbs[2*j+1]};
    }

    f2 XA[8], XB[8];
    float pAq, pAk, pAb;
    LOADX(XA, 0);
    MV3(pAq, pAk, pAb, XA);   // preA_0 = W_0 x_0
    LOADX(XA, 1);             // XA <- x_1

    for (int t = 0; t < SLEN; t += 2) {
      PSTEP(t,     XA, XB);
      PSTEP(t + 1, XB, XA);
    }
  } else {
    // ================= consumer: Wy + y output =================
    f2 Wy2[8];
    {
      const float* py = Wy0 + (hd * DH + r) * DH + c0;
#pragma unroll
      for (int q4 = 0; q4 < 4; ++q4) {
        float4 a = *(const float4*)(py + q4 * 4);
        Wy2[2*q4] = f2{a.x, a.y}; Wy2[2*q4+1] = f2{a.z, a.w};
      }
    }
    f2 XA[8], XB[8];
    LOADX(XA, 0);
    LOADX(XB, 1);

    for (int t = 0; t < SLEN; t += 2) {
      CSTEP(t,     XA);
      CSTEP(t + 1, XB);
    }
  }
}

// ---------- phase 3: out = h + ys @ Wout^T  (in-place over ys==out) ----------

__global__ __launch_bounds__(256)
void srwm_proj(const float* __restrict__ h, const float* __restrict__ ys,
               const float* __restrict__ Wout, float* __restrict__ out) {
  __shared__ float ytile[32][256];
  const int r0  = blockIdx.x * 32;
  const int tid = threadIdx.x;

  const float4* src = (const float4*)(ys + (size_t)r0 * 256);
  float4*       dst = (float4*)(&ytile[0][0]);
#pragma unroll
  for (int i = 0; i < 8; ++i) dst[tid + i * 256] = src[tid + i * 256];
  __syncthreads();

  float acc[32];
#pragma unroll
  for (int m = 0; m < 32; ++m) acc[m] = 0.f;

  const float* wrow = Wout + (size_t)tid * 256;
  for (int k = 0; k < 256; k += 4) {
    float4 w = *(const float4*)(wrow + k);
#pragma unroll
    for (int m = 0; m < 32; ++m) {
      float4 y4 = *(const float4*)(&ytile[m][k]);
      acc[m] = fmaf(w.x, y4.x,
               fmaf(w.y, y4.y,
               fmaf(w.z, y4.z,
               fmaf(w.w, y4.w, acc[m]))));
    }
  }

#pragma unroll
  for (int m = 0; m < 32; ++m) {
    int row = r0 + m;
    out[(size_t)row * 256 + tid] = h[(size_t)row * 256 + tid] + acc[m];
  }
}

// ---------- launcher ----------

extern "C" void kernel_launch(void* const* d_in, const int* in_sizes, int n_in,
                              void* d_out, int out_size, void* d_ws, size_t ws_size,
                              hipStream_t stream) {
  const float* h    = (const float*)d_in[0];
  const float* Wy0  = (const float*)d_in[1];
  const float* Wq0  = (const float*)d_in[2];
  const float* Wk0  = (const float*)d_in[3];
  const float* wb0  = (const float*)d_in[4];
  const float* Wout = (const float*)d_in[5];
  float* out = (float*)d_out;

  srwm_xsm <<<SLEN * HSTRIDE / 256, 256, 0, stream>>>(h, out);
  srwm_scan<<<64, 128, 0, stream>>>(Wy0, Wq0, Wk0, wb0, out);
  srwm_proj<<<256, 256, 0, stream>>>(h, out, Wout, out);
}

// Round 9
// 674.533 us; speedup vs baseline: 1.1951x; 1.1951x over previous
//
#include <hip/hip_runtime.h>

#define DEV __device__ __forceinline__

typedef float f2 __attribute__((ext_vector_type(2)));

// packed fp32 fma: acc.lo += a.lo*b.lo ; acc.hi += a.hi*b.hi  (VOP3P)
DEV void pkfma(f2& acc, f2 a, f2 b) {
  asm("v_pk_fma_f32 %0, %1, %2, %0" : "+v"(acc) : "v"(a), "v"(b));
}

template <int CTRL>
DEV float dppf(float x) {
  return __int_as_float(__builtin_amdgcn_update_dpp(
      0, __float_as_int(x), CTRL, 0xF, 0xF, true));
}

// Butterfly sum within each 32-lane half; result broadcast to the half.
DEV float wsum32(float v) {
  v += dppf<0xB1>(v);   // xor1
  v += dppf<0x4E>(v);   // xor2
  v += dppf<0x141>(v);  // xor4
  v += dppf<0x140>(v);  // xor8
#if __has_builtin(__builtin_amdgcn_permlane16_swap)
  {
    auto p = __builtin_amdgcn_permlane16_swap(
        __float_as_uint(v), __float_as_uint(v), false, false);
    v = __uint_as_float(p[0]) + __uint_as_float(p[1]);
  }
#else
  v += __shfl_xor(v, 16, 64);
#endif
  return v;
}

// v[l] + v[l^32]
DEV float halfsum(float v) {
#if __has_builtin(__builtin_amdgcn_permlane32_swap)
  auto p = __builtin_amdgcn_permlane32_swap(
      __float_as_uint(v), __float_as_uint(v), false, false);
  return __uint_as_float(p[0]) + __uint_as_float(p[1]);
#else
  return v + __shfl_xor(v, 32, 64);
#endif
}

DEV float rlane(float v, int l) {
  return __int_as_float(__builtin_amdgcn_readlane(__float_as_int(v), l));
}

#define SLEN 1024
#define NH 8
#define DH 32
#define HSTRIDE 2048  // floats per timestep (B*NH*DH)

// ---------- phase 1: x = softmax32(h), staged into d_out ----------

__global__ __launch_bounds__(256)
void srwm_xsm(const float* __restrict__ h, float* __restrict__ x) {
  int i = blockIdx.x * 256 + threadIdx.x;
  float e = __expf(h[i]);
  x[i] = __fdividef(e, wsum32(e));
}

// ---------- phase 2: single-wave scan, packed fp32, no barriers ----------
// Lane (r = lane&31, c0 = 0|16) holds cols c0..c0+15 (as 8 f2 column-pairs)
// of row r for Wy,Wq,Wk, and wb^T chunk wb[c0+j][r&3] for WB.
//
// Deferred-update recurrence (identical math to the verified R3 kernel):
// entering step T: a_T = (aY,aQ,aK,aB) = W_T x_T readouts; W regs = W_{T-1};
// u_{T-1} scalars; KCin = k_{T-1} column chunks (read last step).
//   1. W += u_{T-1} (x) KCin            (off-path, fills softmax bubbles)
//   2. q,k = softmax(aQ,aK); Bs = sigmoid(aB); dv = q - k
//   3. dvs[r]=dv, kvs[r]=k; read back col chunks DV, KCout
//      (same-wave DS ordering; only the read's lgkm wait lands)
//   4. y_T = aY -> global; prefetch x_{T+2}
//   5. preA = W_T x_{T+1}               (under the LDS read latency)
//   6. d = W_T DV ; s = KCout . x_{T+1}
//   7. u_T = B*d ; a_{T+1} = preA + u_T * s

#define LOADX(DST, T)                                                         \
  { const float* xp_ = xb + (size_t)(T) * HSTRIDE + c0;                       \
    _Pragma("unroll") for (int q4 = 0; q4 < 4; ++q4) {                        \
      float4 a_ = *(const float4*)(xp_ + q4 * 4);                             \
      DST[2*q4] = f2{a_.x, a_.y}; DST[2*q4+1] = f2{a_.z, a_.w}; } }

#define MVDOT(OUT, M, V)                                                      \
  { f2 _a0 = {0.f, 0.f}, _a1 = {0.f, 0.f};                                    \
    _Pragma("unroll") for (int _j = 0; _j < 8; _j += 2) {                     \
      pkfma(_a0, M[_j], V[_j]); pkfma(_a1, M[_j+1], V[_j+1]); }               \
    f2 _as = _a0 + _a1; OUT = halfsum(_as.x + _as.y); }

#define STEP(T, XS, XN, KCin, KCout)                                          \
  {                                                                           \
    /* 1. W <- W_T (u_{T-1} (x) k_{T-1}); off-path register work */           \
    f2 uuY = {uY, uY}, uuQ = {uQ, uQ}, uuK = {uK, uK}, uuB = {uB, uB};        \
    _Pragma("unroll") for (int j = 0; j < 8; ++j) {                           \
      pkfma(Wy2[j], uuY, KCin[j]);                                            \
      pkfma(Wq2[j], uuQ, KCin[j]);                                            \
      pkfma(Wk2[j], uuK, KCin[j]);                                            \
      pkfma(WB2[j], uuB, KCin[j]);                                            \
    }                                                                         \
    /* 2. softmax / sigmoid on a_T */                                         \
    float eq_ = __expf(aQ), ek_ = __expf(aK);                                 \
    float q_  = __fdividef(eq_, wsum32(eq_));                                 \
    float k_  = __fdividef(ek_, wsum32(ek_));                                 \
    float bs_ = __fdividef(1.f, 1.f + __expf(-aB));                           \
    float B0_ = rlane(bs_, 0), B1_ = rlane(bs_, 1);                           \
    float B2_ = rlane(bs_, 2), B3_ = rlane(bs_, 3);                           \
    float dv_ = q_ - k_;                                                      \
    /* 3. in-wave transpose via LDS (write then read, same wave) */           \
    dvs[r] = dv_;                                                             \
    kvs[r] = k_;                                                              \
    f2 DV[8];                                                                 \
    { float4 t0_ = *(const float4*)&dvs[c0];                                  \
      float4 t1_ = *(const float4*)&dvs[c0 + 4];                              \
      float4 t2_ = *(const float4*)&dvs[c0 + 8];                              \
      float4 t3_ = *(const float4*)&dvs[c0 + 12];                             \
      DV[0] = f2{t0_.x, t0_.y}; DV[1] = f2{t0_.z, t0_.w};                     \
      DV[2] = f2{t1_.x, t1_.y}; DV[3] = f2{t1_.z, t1_.w};                     \
      DV[4] = f2{t2_.x, t2_.y}; DV[5] = f2{t2_.z, t2_.w};                     \
      DV[6] = f2{t3_.x, t3_.y}; DV[7] = f2{t3_.z, t3_.w};                     \
      float4 u0_ = *(const float4*)&kvs[c0];                                  \
      float4 u1_ = *(const float4*)&kvs[c0 + 4];                              \
      float4 u2_ = *(const float4*)&kvs[c0 + 8];                              \
      float4 u3_ = *(const float4*)&kvs[c0 + 12];                             \
      KCout[0] = f2{u0_.x, u0_.y}; KCout[1] = f2{u0_.z, u0_.w};               \
      KCout[2] = f2{u1_.x, u1_.y}; KCout[3] = f2{u1_.z, u1_.w};               \
      KCout[4] = f2{u2_.x, u2_.y}; KCout[5] = f2{u2_.z, u2_.w};               \
      KCout[6] = f2{u3_.x, u3_.y}; KCout[7] = f2{u3_.z, u3_.w}; }             \
    /* 4. y emit + x prefetch (latency spans ~2 steps) */                     \
    if (lane < DH) xb[(size_t)(T) * HSTRIDE + lane] = aY;                     \
    int t2n_ = (T) + 2; if (t2n_ > SLEN - 1) t2n_ = SLEN - 1;                 \
    LOADX(XN, t2n_);                                                          \
    /* 5. preA = W_T x_{T+1} (register-only; hides LDS read latency) */       \
    float pY_, pQ_, pK_, pB_;                                                 \
    MVDOT(pY_, Wy2, XS); MVDOT(pQ_, Wq2, XS);                                 \
    MVDOT(pK_, Wk2, XS); MVDOT(pB_, WB2, XS);                                 \
    /* 6. d = W_T dv (cols) ; s = k_T . x_{T+1} */                            \
    float dY_, dQ_, dK_, dB_;                                                 \
    MVDOT(dY_, Wy2, DV); MVDOT(dQ_, Wq2, DV);                                 \
    MVDOT(dK_, Wk2, DV); MVDOT(dB_, WB2, DV);                                 \
    f2 s0_ = {0.f, 0.f}, s1_ = {0.f, 0.f};                                    \
    _Pragma("unroll") for (int j = 0; j < 8; j += 2) {                        \
      pkfma(s0_, KCout[j], XS[j]); pkfma(s1_, KCout[j+1], XS[j+1]); }         \
    f2 ss_ = s0_ + s1_; float s_ = halfsum(ss_.x + ss_.y);                    \
    /* 7. u_T ; a_{T+1} = preA + u_T * s */                                   \
    uY = B0_ * dY_; uQ = B1_ * dQ_; uK = B2_ * dK_; uB = B3_ * dB_;           \
    aY = fmaf(uY, s_, pY_); aQ = fmaf(uQ, s_, pQ_);                           \
    aK = fmaf(uK, s_, pK_); aB = fmaf(uB, s_, pB_);                           \
  }

__global__ __launch_bounds__(64, 1)
void srwm_scan(const float* __restrict__ Wy0, const float* __restrict__ Wq0,
               const float* __restrict__ Wk0, const float* __restrict__ wb0,
               float* xy) {
  __shared__ float dvs[DH];
  __shared__ float kvs[DH];

  const int bh   = blockIdx.x;   // 0..63
  const int hd   = bh & 7;
  const int lane = threadIdx.x;
  const int r    = lane & 31;
  const int c0   = (lane >> 5) * 16;
  const int kk   = r & 3;

  // ---- load state as packed column-pairs ----
  f2 Wy2[8], Wq2[8], Wk2[8], WB2[8];
  {
    const float* py = Wy0 + (hd * DH + r) * DH + c0;
    const float* pq = Wq0 + (hd * DH + r) * DH + c0;
    const float* pk = Wk0 + (hd * DH + r) * DH + c0;
#pragma unroll
    for (int q4 = 0; q4 < 4; ++q4) {
      float4 a = *(const float4*)(py + q4 * 4);
      Wy2[2*q4] = f2{a.x, a.y}; Wy2[2*q4+1] = f2{a.z, a.w};
      float4 b = *(const float4*)(pq + q4 * 4);
      Wq2[2*q4] = f2{b.x, b.y}; Wq2[2*q4+1] = f2{b.z, b.w};
      float4 c = *(const float4*)(pk + q4 * 4);
      Wk2[2*q4] = f2{c.x, c.y}; Wk2[2*q4+1] = f2{c.z, c.w};
    }
#pragma unroll
    for (int j = 0; j < 8; ++j)
      WB2[j] = f2{wb0[(hd * DH + c0 + 2*j) * 4 + kk],
                  wb0[(hd * DH + c0 + 2*j + 1) * 4 + kk]};
  }

  float* xb = xy + bh * DH;  // x/y for this (b,h): [t*HSTRIDE + j]

  // ---- prologue: a_0 = W_0 x_0 ; X0 <- x_1 ; u_{-1}=0, KC=0 ----
  f2 X0[8], X1[8];
  LOADX(X0, 0);
  float aY, aQ, aK, aB;
  MVDOT(aY, Wy2, X0); MVDOT(aQ, Wq2, X0);
  MVDOT(aK, Wk2, X0); MVDOT(aB, WB2, X0);
  LOADX(X0, 1);

  f2 KCa[8], KCb[8];
#pragma unroll
  for (int j = 0; j < 8; ++j) KCa[j] = f2{0.f, 0.f};
  float uY = 0.f, uQ = 0.f, uK = 0.f, uB = 0.f;

  for (int t = 0; t < SLEN; t += 2) {
    STEP(t,     X0, X1, KCa, KCb);
    STEP(t + 1, X1, X0, KCb, KCa);
  }
}

// ---------- phase 3: out = h + ys @ Wout^T  (in-place over ys==out) ----------

__global__ __launch_bounds__(256)
void srwm_proj(const float* __restrict__ h, const float* __restrict__ ys,
               const float* __restrict__ Wout, float* __restrict__ out) {
  __shared__ float ytile[32][256];
  const int r0  = blockIdx.x * 32;
  const int tid = threadIdx.x;

  const float4* src = (const float4*)(ys + (size_t)r0 * 256);
  float4*       dst = (float4*)(&ytile[0][0]);
#pragma unroll
  for (int i = 0; i < 8; ++i) dst[tid + i * 256] = src[tid + i * 256];
  __syncthreads();

  float acc[32];
#pragma unroll
  for (int m = 0; m < 32; ++m) acc[m] = 0.f;

  const float* wrow = Wout + (size_t)tid * 256;
  for (int k = 0; k < 256; k += 4) {
    float4 w = *(const float4*)(wrow + k);
#pragma unroll
    for (int m = 0; m < 32; ++m) {
      float4 y4 = *(const float4*)(&ytile[m][k]);
      acc[m] = fmaf(w.x, y4.x,
               fmaf(w.y, y4.y,
               fmaf(w.z, y4.z,
               fmaf(w.w, y4.w, acc[m]))));
    }
  }

#pragma unroll
  for (int m = 0; m < 32; ++m) {
    int row = r0 + m;
    out[(size_t)row * 256 + tid] = h[(size_t)row * 256 + tid] + acc[m];
  }
}

// ---------- launcher ----------

extern "C" void kernel_launch(void* const* d_in, const int* in_sizes, int n_in,
                              void* d_out, int out_size, void* d_ws, size_t ws_size,
                              hipStream_t stream) {
  const float* h    = (const float*)d_in[0];
  const float* Wy0  = (const float*)d_in[1];
  const float* Wq0  = (const float*)d_in[2];
  const float* Wk0  = (const float*)d_in[3];
  const float* wb0  = (const float*)d_in[4];
  const float* Wout = (const float*)d_in[5];
  float* out = (float*)d_out;

  // d_out triple duty: x (phase1) -> progressively overwritten by y (phase2)
  // -> final output (phase3, in-place via LDS tile).
  srwm_xsm <<<SLEN * HSTRIDE / 256, 256, 0, stream>>>(h, out);
  srwm_scan<<<64, 64, 0, stream>>>(Wy0, Wq0, Wk0, wb0, out);
  srwm_proj<<<256, 256, 0, stream>>>(h, out, Wout, out);
}

// Round 10
// 591.516 us; speedup vs baseline: 1.3628x; 1.1403x over previous
//
#include <hip/hip_runtime.h>

#define DEV __device__ __forceinline__

// ---------- cross-lane helpers (all VALU, no LDS) ----------

template <int CTRL>
DEV float dppf(float x) {
  return __int_as_float(__builtin_amdgcn_update_dpp(
      0, __float_as_int(x), CTRL, 0xF, 0xF, true));
}

// Butterfly sum within each 32-lane half; result broadcast to the half.
DEV float wsum32(float v) {
  v += dppf<0xB1>(v);   // xor1
  v += dppf<0x4E>(v);   // xor2
  v += dppf<0x141>(v);  // xor4
  v += dppf<0x140>(v);  // xor8
#if __has_builtin(__builtin_amdgcn_permlane16_swap)
  {
    auto p = __builtin_amdgcn_permlane16_swap(
        __float_as_uint(v), __float_as_uint(v), false, false);
    v = __uint_as_float(p[0]) + __uint_as_float(p[1]);
  }
#else
  v += __shfl_xor(v, 16, 64);
#endif
  return v;
}

// v[l] + v[l^32]
DEV float halfsum(float v) {
#if __has_builtin(__builtin_amdgcn_permlane32_swap)
  auto p = __builtin_amdgcn_permlane32_swap(
      __float_as_uint(v), __float_as_uint(v), false, false);
  return __uint_as_float(p[0]) + __uint_as_float(p[1]);
#else
  return v + __shfl_xor(v, 32, 64);
#endif
}

#define SLEN 1024
#define NH 8
#define DH 32
#define HSTRIDE 2048  // floats per timestep (B*NH*DH)

// ---------- phase 1: x = softmax32(h), staged into d_out ----------

__global__ __launch_bounds__(256)
void srwm_xsm(const float* __restrict__ h, float* __restrict__ x) {
  int i = blockIdx.x * 256 + threadIdx.x;
  float e = __expf(h[i]);
  x[i] = __fdividef(e, wsum32(e));
}

// ---------- phase 2: the scan. One block (4 waves) per (b,h). ----------
// Wave w owns one matrix: 0:Wy 1:Wq 2:Wk 3:wb^T. Lane (r=lane&31, c0) holds
// cols c0..c0+15 of row r (w<3) or wb^T chunk wb[c0+j][r&3] (w==3).
//
// Deferred-update recurrence (identical math to R6):
// entering region T: regs hold q_{T-1},k_{T-1} (QV,KV float4x4), B_{T-1}[w]
// (BW); W = W_{T-1}; preA = W_{T-1} x_T. XS = x_T, XP = x_{T+1}.
//
// KEY FIX vs R6: the post-barrier reads of q_T/k_T/B_T are INLINE-ASM
// ds_read (volatile -> pinned right after s_barrier; compiler cannot sink
// them to their use site, which R5-R7 silently did per VGPR=56). The wait
// (lgkmcnt(0)+sched_barrier) is at the NEXT region's entry, so the ~120cy
// LDS latency hides under W-update + x-prefetch + preA (~60 reg-only instrs).
//
// Shared layout (one block so asm offsets are immediates):
//   slot P (P=0,1), stride 288B: q[32]@+0, k[32]@+128B, B[4]@+256B.

#define DSR128(dst, addr, off) \
  asm volatile("ds_read_b128 %0, %1 offset:%2" : "=&v"(dst) : "v"(addr), "i"(off))
#define DSR32(dst, addr, off) \
  asm volatile("ds_read_b32 %0, %1 offset:%2" : "=&v"(dst) : "v"(addr), "i"(off))

#define REGION(T, P, QV, KV, BW, QN, KN, BN, XS, XP)                          \
  {                                                                           \
    /* wait for the asm ds_reads issued in the PREVIOUS region */             \
    asm volatile("s_waitcnt lgkmcnt(0)");                                     \
    __builtin_amdgcn_sched_barrier(0);                                        \
    /* ---- on-path: dv, d-matvec + s-dot, u, a_T ---- */                     \
    float d0=0.f,d1=0.f,d2=0.f,d3=0.f,s0=0.f,s1=0.f,s2=0.f,s3=0.f;            \
    _Pragma("unroll") for (int i = 0; i < 4; ++i) {                           \
      float4 qv = QV[i], kv = KV[i], xv = XS[i];                              \
      d0 = fmaf(W[4*i+0], qv.x - kv.x, d0);                                   \
      d1 = fmaf(W[4*i+1], qv.y - kv.y, d1);                                   \
      d2 = fmaf(W[4*i+2], qv.z - kv.z, d2);                                   \
      d3 = fmaf(W[4*i+3], qv.w - kv.w, d3);                                   \
      s0 = fmaf(kv.x, xv.x, s0);                                              \
      s1 = fmaf(kv.y, xv.y, s1);                                              \
      s2 = fmaf(kv.z, xv.z, s2);                                              \
      s3 = fmaf(kv.w, xv.w, s3);                                              \
    }                                                                         \
    float dsum = halfsum((d0 + d1) + (d2 + d3));                              \
    float sv   = halfsum((s0 + s1) + (s2 + s3));                              \
    float u  = BW * dsum;                                                     \
    float aA = fmaf(u, sv, preA);                                             \
    if (w == 0) {                                                             \
      if (lane < DH) xb[(size_t)(T) * HSTRIDE + lane] = aA;  /* y_T */        \
    } else if (w == 1) {                                                      \
      float e = __expf(aA); shb[(P)*72 + r] = __fdividef(e, wsum32(e));       \
    } else if (w == 2) {                                                      \
      float e = __expf(aA); shb[(P)*72 + 32 + r] = __fdividef(e, wsum32(e));  \
    } else {                                                                  \
      float sg = __fdividef(1.f, 1.f + __expf(-aA));                          \
      if (lane < 4) shb[(P)*72 + 64 + lane] = sg;                             \
    }                                                                         \
    __builtin_amdgcn_sched_barrier(0);                                        \
    asm volatile("s_waitcnt lgkmcnt(0)");                                     \
    __builtin_amdgcn_sched_barrier(0);                                        \
    __builtin_amdgcn_s_barrier();                                             \
    __builtin_amdgcn_sched_barrier(0);                                        \
    /* ---- pinned async reads of slot P (waited next region) ---- */         \
    DSR128(QN[0], adC, (P)*288 +   0);                                        \
    DSR128(QN[1], adC, (P)*288 +  16);                                        \
    DSR128(QN[2], adC, (P)*288 +  32);                                        \
    DSR128(QN[3], adC, (P)*288 +  48);                                        \
    DSR128(KN[0], adC, (P)*288 + 128);                                        \
    DSR128(KN[1], adC, (P)*288 + 144);                                        \
    DSR128(KN[2], adC, (P)*288 + 160);                                        \
    DSR128(KN[3], adC, (P)*288 + 176);                                        \
    DSR32 (BN,    adB, (P)*288 + 256);                                        \
    __builtin_amdgcn_sched_barrier(0);                                        \
    /* ---- hidden under the reads: W<-W_T (old k), prefetch, preA ---- */    \
    _Pragma("unroll") for (int i = 0; i < 4; ++i) {                           \
      float4 kv = KV[i];                                                      \
      W[4*i+0] = fmaf(u, kv.x, W[4*i+0]);                                     \
      W[4*i+1] = fmaf(u, kv.y, W[4*i+1]);                                     \
      W[4*i+2] = fmaf(u, kv.z, W[4*i+2]);                                     \
      W[4*i+3] = fmaf(u, kv.w, W[4*i+3]);                                     \
    }                                                                         \
    int t2 = (T) + 2; if (t2 > SLEN - 1) t2 = SLEN - 1;                       \
    { const float* xp_ = xb + (size_t)t2 * HSTRIDE + c0;                      \
      _Pragma("unroll") for (int i = 0; i < 4; ++i)                           \
        XS[i] = *(const float4*)(xp_ + 4 * i); }                              \
    float p0=0.f,p1=0.f,p2=0.f,p3=0.f;                                        \
    _Pragma("unroll") for (int i = 0; i < 4; ++i) {                           \
      float4 xv = XP[i];                                                      \
      p0 = fmaf(W[4*i+0], xv.x, p0);                                          \
      p1 = fmaf(W[4*i+1], xv.y, p1);                                          \
      p2 = fmaf(W[4*i+2], xv.z, p2);                                          \
      p3 = fmaf(W[4*i+3], xv.w, p3);                                          \
    }                                                                         \
    preA = halfsum((p0 + p1) + (p2 + p3));                                    \
  }

__global__ __launch_bounds__(256, 1)
void srwm_scan(const float* __restrict__ Wy0, const float* __restrict__ Wq0,
               const float* __restrict__ Wk0, const float* __restrict__ wb0,
               float* xy) {
  __shared__ float shb[2 * 72];  // slot P: q@0, k@32, B@64 (floats)

  const int bh   = blockIdx.x;        // 0..63
  const int hd   = bh & 7;
  const int w    = threadIdx.x >> 6;  // wave: 0..3
  const int lane = threadIdx.x & 63;
  const int r    = lane & 31;
  const int c0   = (lane >> 5) * 16;

  // LDS byte addresses for the asm reads (low 32 bits of generic = LDS offset)
  const uint32_t lbase = (uint32_t)(uintptr_t)&shb[0];
  const uint32_t adC   = lbase + c0 * 4;   // chunk reads (q/k)
  const uint32_t adB   = lbase + w * 4;    // per-wave beta read (uniform)

  // ---- load this wave's matrix ----
  float W[16];
  if (w < 3) {
    const float* src = (w == 0) ? Wy0 : (w == 1) ? Wq0 : Wk0;
    const float* p = src + (hd * DH + r) * DH + c0;
#pragma unroll
    for (int j = 0; j < 16; j += 4) *(float4*)&W[j] = *(const float4*)(p + j);
  } else {
    const int kk = r & 3;
#pragma unroll
    for (int j = 0; j < 16; ++j) W[j] = wb0[(hd * DH + c0 + j) * 4 + kk];
  }

  float* xb = xy + bh * DH;  // x/y for this (b,h): element [t*HSTRIDE + j]

  // ---- prologue: X0 <- x_0, X1 <- x_1; q_{-1}=k_{-1}=0, B_{-1}=0 in regs;
  //      preA = W_0 x_0 (u_{-1}=0 so W_{-1} == W_0) ----
  float4 X0[4], X1[4];
#pragma unroll
  for (int i = 0; i < 4; ++i) {
    X0[i] = *(const float4*)(xb + c0 + 4 * i);
    X1[i] = *(const float4*)(xb + HSTRIDE + c0 + 4 * i);
  }
  float p0 = 0.f, p1 = 0.f, p2 = 0.f, p3 = 0.f;
#pragma unroll
  for (int i = 0; i < 4; ++i) {
    float4 xv = X0[i];
    p0 = fmaf(W[4*i+0], xv.x, p0);
    p1 = fmaf(W[4*i+1], xv.y, p1);
    p2 = fmaf(W[4*i+2], xv.z, p2);
    p3 = fmaf(W[4*i+3], xv.w, p3);
  }
  float preA = halfsum((p0 + p1) + (p2 + p3));

  float4 QA[4], KA[4], QB[4], KB[4];
  const float4 z4 = {0.f, 0.f, 0.f, 0.f};
#pragma unroll
  for (int i = 0; i < 4; ++i) { QA[i] = z4; KA[i] = z4; }
  float BwA = 0.f, BwB = 0.f;

  __syncthreads();

  for (int t = 0; t < SLEN; t += 2) {
    REGION(t,     0, QA, KA, BwA, QB, KB, BwB, X0, X1);
    REGION(t + 1, 1, QB, KB, BwB, QA, KA, BwA, X1, X0);
  }
}

// ---------- phase 3: out = h + ys @ Wout^T  (in-place over ys==out) ----------

__global__ __launch_bounds__(256)
void srwm_proj(const float* __restrict__ h, const float* __restrict__ ys,
               const float* __restrict__ Wout, float* __restrict__ out) {
  __shared__ float ytile[32][256];  // 32 KB
  const int r0  = blockIdx.x * 32;
  const int tid = threadIdx.x;

  const float4* src = (const float4*)(ys + (size_t)r0 * 256);
  float4*       dst = (float4*)(&ytile[0][0]);
#pragma unroll
  for (int i = 0; i < 8; ++i) dst[tid + i * 256] = src[tid + i * 256];
  __syncthreads();

  float acc[32];
#pragma unroll
  for (int m = 0; m < 32; ++m) acc[m] = 0.f;

  const float* wrow = Wout + (size_t)tid * 256;
  for (int k = 0; k < 256; k += 4) {
    float4 wv = *(const float4*)(wrow + k);
#pragma unroll
    for (int m = 0; m < 32; ++m) {
      float4 y4 = *(const float4*)(&ytile[m][k]);
      acc[m] = fmaf(wv.x, y4.x,
               fmaf(wv.y, y4.y,
               fmaf(wv.z, y4.z,
               fmaf(wv.w, y4.w, acc[m]))));
    }
  }

#pragma unroll
  for (int m = 0; m < 32; ++m) {
    int row = r0 + m;
    out[(size_t)row * 256 + tid] = h[(size_t)row * 256 + tid] + acc[m];
  }
}

// ---------- launcher ----------

extern "C" void kernel_launch(void* const* d_in, const int* in_sizes, int n_in,
                              void* d_out, int out_size, void* d_ws, size_t ws_size,
                              hipStream_t stream) {
  const float* h    = (const float*)d_in[0];
  const float* Wy0  = (const float*)d_in[1];
  const float* Wq0  = (const float*)d_in[2];
  const float* Wk0  = (const float*)d_in[3];
  const float* wb0  = (const float*)d_in[4];
  const float* Wout = (const float*)d_in[5];
  float* out = (float*)d_out;

  // d_out triple duty: x (phase1) -> progressively overwritten by y (phase2)
  // -> final output (phase3, in-place via LDS tile).
  srwm_xsm <<<SLEN * HSTRIDE / 256, 256, 0, stream>>>(h, out);
  srwm_scan<<<64, 256, 0, stream>>>(Wy0, Wq0, Wk0, wb0, out);
  srwm_proj<<<256, 256, 0, stream>>>(h, out, Wout, out);
}